// Round 2
// baseline (664.661 us; speedup 1.0000x reference)
//
#include <hip/hip_runtime.h>
#include <hip/hip_cooperative_groups.h>

// EMA scan: out[l,b,d,e] = dec[e]*x[l,b,d] + (1-dec[e])*out[l-1,b,d,e],
// init state = x[0,b,d]. dec = sigmoid(log_decay).
//
// R8: single cooperative kernel, exact chunk-carry decomposition.
//   R7 (3 kernels: agg / scan / main) == R6 halo time (68us) despite 5x less
//   work -> slack is not compute: it's the 2 graph-edge gaps, kernel C's
//   read-front (x refetch 33.5MB + carry 8MB before any store), and B's
//   latency-bound scan. Fix: fuse. Phase 1 keeps x in REGISTERS (xv[32]),
//   phase 2 scans carries on blocks 0..63, phase 3 is a pure store loop
//   (reads only 32B of carry). Grid-wide sync via cooperative launch;
//   __launch_bounds__(256,4) guarantees 4 blocks/CU co-residency (1024 = 256CU*4).

namespace cg = cooperative_groups;

#define LL    4096
#define BB    16
#define DD    128
#define EMAS  8
#define BDSZ  (BB * DD)              // 2048
#define CHUNK 32
#define NCHUNK (LL / CHUNK)          // 128
#define SLICE (BDSZ * EMAS)          // 16384 floats per chunk slice in ws
#define WS_BYTES ((size_t)NCHUNK * SLICE * sizeof(float))   // 8 MiB

typedef float f32x4 __attribute__((ext_vector_type(4)));

__device__ __forceinline__ void load_decays(const float* __restrict__ log_decay,
                                            float* dec, float* a) {
#pragma unroll
    for (int e = 0; e < EMAS; ++e) {
        const float ld = log_decay[e];
        const float dd = 1.0f / (1.0f + __expf(-ld));
        dec[e] = dd;
        a[e]   = 1.0f - dd;
    }
}

// ---------------- R8 fused cooperative kernel ----------------
__global__ __launch_bounds__(256, 4) void ema_fused(const float* __restrict__ x,
                                                    const float* __restrict__ log_decay,
                                                    float* __restrict__ hws,
                                                    float* __restrict__ out) {
    const int tid   = threadIdx.x;
    const int chunk = blockIdx.x >> 3;
    const int off   = ((blockIdx.x & 7) << 8) + tid;   // == b*DD + d

    float dec[EMAS], a[EMAS];
    load_decays(log_decay, dec, a);

    // ---- Phase 1: per-chunk aggregate; x stays in registers for phase 3 ----
    const float* xp = x + (size_t)chunk * CHUNK * BDSZ + off;
    float xv[CHUNK];
#pragma unroll
    for (int k = 0; k < CHUNK; ++k) xv[k] = xp[(size_t)k * BDSZ];

    float s[EMAS];
#pragma unroll
    for (int e = 0; e < EMAS; ++e) s[e] = 0.0f;
#pragma unroll
    for (int k = 0; k < CHUNK; ++k) {
        const float xk = xv[k];
#pragma unroll
        for (int e = 0; e < EMAS; ++e) s[e] = fmaf(a[e], s[e], dec[e] * xk);
    }
    {
        f32x4* hp = (f32x4*)(hws + (size_t)chunk * SLICE + (size_t)off * EMAS);
        f32x4 lo = {s[0], s[1], s[2], s[3]};
        f32x4 hi = {s[4], s[5], s[6], s[7]};
        hp[0] = lo;
        hp[1] = hi;
    }

    cg::grid_group grid = cg::this_grid();
    __threadfence();
    grid.sync();

    // ---- Phase 2: carry scan across chunks, blocks 0..63 only ----
    // carry_0 = x[0,b,d]; carry_{c+1} = a^32*carry_c + h_c. In-place in hws.
    if (blockIdx.x < 64) {
        const int t  = blockIdx.x * 256 + tid;   // 0..16383 == (b,d,e)
        const int e  = t & (EMAS - 1);
        const int bd = t >> 3;

        const float ld2 = log_decay[e];          // recompute (runtime e would
        const float d2  = 1.0f / (1.0f + __expf(-ld2));  // scratch-spill a[])
        float A = 1.0f - d2;                     // a
        A = A * A;                               // a^2
        A = A * A;                               // a^4
        A = A * A;                               // a^8
        A = A * A;                               // a^16
        A = A * A;                               // a^32

        float sc  = x[bd];                       // carry into chunk 0
        float* hp = hws + t;

#define PF 8
        float buf[PF];
#pragma unroll
        for (int i = 0; i < PF; ++i) buf[i] = hp[(size_t)i * SLICE];
        for (int c0 = 0; c0 < NCHUNK; c0 += PF) {
            float nbuf[PF];
            if (c0 + PF < NCHUNK) {
#pragma unroll
                for (int i = 0; i < PF; ++i) nbuf[i] = hp[(size_t)(c0 + PF + i) * SLICE];
            } else {
#pragma unroll
                for (int i = 0; i < PF; ++i) nbuf[i] = 0.0f;
            }
#pragma unroll
            for (int i = 0; i < PF; ++i) {
                const float hv = buf[i];
                hp[(size_t)(c0 + i) * SLICE] = sc;   // publish carry into c0+i
                sc = fmaf(A, sc, hv);                // carry into next chunk
            }
#pragma unroll
            for (int i = 0; i < PF; ++i) buf[i] = nbuf[i];
        }
#undef PF
    }

    __threadfence();
    grid.sync();

    // ---- Phase 3: pure store loop (reads 32B carry, x already in regs) ----
    {
        const f32x4* cp = (const f32x4*)(hws + (size_t)chunk * SLICE + (size_t)off * EMAS);
        f32x4 clo = cp[0];
        f32x4 chi = cp[1];
#pragma unroll
        for (int i = 0; i < 4; ++i) { s[i] = clo[i]; s[4 + i] = chi[i]; }

        f32x4* op = (f32x4*)(out + ((size_t)chunk * CHUNK * BDSZ + off) * EMAS);
        const int opstride = SLICE / 4;          // f32x4s per l-step
#pragma unroll
        for (int k = 0; k < CHUNK; ++k) {
            const float xk = xv[k];
#pragma unroll
            for (int e = 0; e < EMAS; ++e) s[e] = fmaf(a[e], s[e], dec[e] * xk);
            f32x4 lo = {s[0], s[1], s[2], s[3]};
            f32x4 hi = {s[4], s[5], s[6], s[7]};
            op[0] = lo;
            op[1] = hi;
            op += opstride;
        }
    }
}

// ---------------- R7 fallback: 3-kernel exact path ----------------
__global__ __launch_bounds__(256) void ema_agg(const float* __restrict__ x,
                                               const float* __restrict__ log_decay,
                                               float* __restrict__ hws) {
    const int tid   = threadIdx.x;
    const int chunk = blockIdx.x >> 3;
    const int off   = ((blockIdx.x & 7) << 8) + tid;

    float dec[EMAS], a[EMAS];
    load_decays(log_decay, dec, a);

    const float* xp = x + (size_t)chunk * CHUNK * BDSZ + off;
    float xv[CHUNK];
#pragma unroll
    for (int k = 0; k < CHUNK; ++k) xv[k] = xp[(size_t)k * BDSZ];

    float s[EMAS];
#pragma unroll
    for (int e = 0; e < EMAS; ++e) s[e] = 0.0f;
#pragma unroll
    for (int k = 0; k < CHUNK; ++k) {
        const float xk = xv[k];
#pragma unroll
        for (int e = 0; e < EMAS; ++e) s[e] = fmaf(a[e], s[e], dec[e] * xk);
    }

    f32x4* hp = (f32x4*)(hws + (size_t)chunk * SLICE + (size_t)off * EMAS);
    f32x4 lo = {s[0], s[1], s[2], s[3]};
    f32x4 hi = {s[4], s[5], s[6], s[7]};
    hp[0] = lo;
    hp[1] = hi;
}

__global__ __launch_bounds__(256) void ema_scan(const float* __restrict__ x,
                                                const float* __restrict__ log_decay,
                                                float* __restrict__ hws) {
    const int tid = blockIdx.x * 256 + threadIdx.x;
    const int e   = tid & (EMAS - 1);
    const int bd  = tid >> 3;

    const float ld  = log_decay[e];
    const float dec = 1.0f / (1.0f + __expf(-ld));
    float A = 1.0f - dec;
    A = A * A; A = A * A; A = A * A; A = A * A; A = A * A;   // a^32

    float s = x[bd];
    float* hp = hws + tid;

#define PF 16
    float buf[PF];
#pragma unroll
    for (int i = 0; i < PF; ++i) buf[i] = hp[(size_t)i * SLICE];
    for (int c0 = 0; c0 < NCHUNK; c0 += PF) {
        float nbuf[PF];
        if (c0 + PF < NCHUNK) {
#pragma unroll
            for (int i = 0; i < PF; ++i) nbuf[i] = hp[(size_t)(c0 + PF + i) * SLICE];
        } else {
#pragma unroll
            for (int i = 0; i < PF; ++i) nbuf[i] = 0.0f;
        }
#pragma unroll
        for (int i = 0; i < PF; ++i) {
            const float hv = buf[i];
            hp[(size_t)(c0 + i) * SLICE] = s;
            s = fmaf(A, s, hv);
        }
#pragma unroll
        for (int i = 0; i < PF; ++i) buf[i] = nbuf[i];
    }
#undef PF
}

__global__ __launch_bounds__(256) void ema_main(const float* __restrict__ x,
                                                const float* __restrict__ log_decay,
                                                const float* __restrict__ carry,
                                                float* __restrict__ out) {
    const int tid   = threadIdx.x;
    const int chunk = blockIdx.x >> 3;
    const int off   = ((blockIdx.x & 7) << 8) + tid;

    float dec[EMAS], a[EMAS];
    load_decays(log_decay, dec, a);

    const int cstart = chunk * CHUNK;
    const float* xp  = x + (size_t)cstart * BDSZ + off;

    float xv[CHUNK];
#pragma unroll
    for (int k = 0; k < CHUNK; ++k) xv[k] = xp[(size_t)k * BDSZ];

    const f32x4* cp = (const f32x4*)(carry + (size_t)chunk * SLICE + (size_t)off * EMAS);
    f32x4 clo = cp[0];
    f32x4 chi = cp[1];
    float s[EMAS];
#pragma unroll
    for (int i = 0; i < 4; ++i) { s[i] = clo[i]; s[4 + i] = chi[i]; }

    f32x4* op = (f32x4*)(out + ((size_t)cstart * BDSZ + off) * EMAS);
    const int opstride = SLICE / 4;
#pragma unroll
    for (int k = 0; k < CHUNK; ++k) {
        const float xk = xv[k];
#pragma unroll
        for (int e = 0; e < EMAS; ++e) s[e] = fmaf(a[e], s[e], dec[e] * xk);
        f32x4 lo = {s[0], s[1], s[2], s[3]};
        f32x4 hi = {s[4], s[5], s[6], s[7]};
        op[0] = lo;
        op[1] = hi;
        op += opstride;
    }
}

// ---------------- Last-resort fallback: R6 halo kernel (no ws) ----------------
#define HALO  128
#define U     16

__global__ __launch_bounds__(256) void ema_kernel(const float* __restrict__ x,
                                                  const float* __restrict__ log_decay,
                                                  float* __restrict__ out) {
    const int tid   = threadIdx.x;
    const int d     = tid & (DD - 1);
    const int bsub  = tid >> 7;
    const int bg    = blockIdx.x & 7;
    const int chunk = blockIdx.x >> 3;
    const int b     = bg * 2 + bsub;
    const int off   = b * DD + d;

    float dec[EMAS], a[EMAS];
    load_decays(log_decay, dec, a);

    const int cstart = chunk * CHUNK;
    int l0 = cstart - HALO;
    if (l0 < 0) l0 = 0;
    const int nsteps   = (cstart - l0) + CHUNK;
    const int nblk     = nsteps / U;
    const int halo_blk = (cstart - l0) / U;

    const float* xb = x + (size_t)l0 * BDSZ + off;

    const float s0 = *xb;
    float s[EMAS];
#pragma unroll
    for (int e = 0; e < EMAS; ++e) s[e] = s0;

    f32x4* op = (f32x4*)(out + ((size_t)cstart * BDSZ + off) * EMAS);
    const int opstride = BDSZ * EMAS / 4;

#define LOADBLK(BUF, IDX)                                                      \
    do {                                                                       \
        int _i = (IDX); if (_i > nblk - 1) _i = nblk - 1;                      \
        const float* _p = xb + (size_t)_i * U * BDSZ;                          \
        _Pragma("unroll")                                                      \
        for (int u = 0; u < U; ++u) (BUF)[u] = _p[(size_t)u * BDSZ];           \
    } while (0)

#define PROCESS(BUF, J)                                                        \
    do {                                                                       \
        if ((J) >= halo_blk) {                                                 \
            _Pragma("unroll")                                                  \
            for (int u = 0; u < U; ++u) {                                      \
                const float xv2 = (BUF)[u];                                    \
                _Pragma("unroll")                                              \
                for (int e = 0; e < EMAS; ++e)                                 \
                    s[e] = fmaf(a[e], s[e], dec[e] * xv2);                     \
                f32x4 lo = {s[0], s[1], s[2], s[3]};                           \
                f32x4 hi = {s[4], s[5], s[6], s[7]};                           \
                op[0] = lo;                                                    \
                op[1] = hi;                                                    \
                op += opstride;                                                \
            }                                                                  \
        } else {                                                               \
            _Pragma("unroll")                                                  \
            for (int u = 0; u < U; ++u) {                                      \
                const float xv2 = (BUF)[u];                                    \
                _Pragma("unroll")                                              \
                for (int e = 0; e < EMAS; ++e)                                 \
                    s[e] = fmaf(a[e], s[e], dec[e] * xv2);                     \
            }                                                                  \
        }                                                                      \
    } while (0)

    float b0[U], b1[U], b2[U];
    LOADBLK(b0, 0);
    LOADBLK(b1, 1);

    int j = 0;
    for (; j + 2 < nblk; j += 3) {
        LOADBLK(b2, j + 2);
        PROCESS(b0, j);
        LOADBLK(b0, j + 3);
        PROCESS(b1, j + 1);
        LOADBLK(b1, j + 4);
        PROCESS(b2, j + 2);
    }
    if (j < nblk)     PROCESS(b0, j);
    if (j + 1 < nblk) PROCESS(b1, j + 1);
#undef PROCESS
#undef LOADBLK
}

extern "C" void kernel_launch(void* const* d_in, const int* in_sizes, int n_in,
                              void* d_out, int out_size, void* d_ws, size_t ws_size,
                              hipStream_t stream) {
    const float* x  = (const float*)d_in[0];
    const float* ld = (const float*)d_in[1];
    float* out      = (float*)d_out;
    (void)in_sizes; (void)n_in; (void)out_size;

    if (d_ws && ws_size >= WS_BYTES) {
        float* hws = (float*)d_ws;
        void* args[] = {(void*)&x, (void*)&ld, (void*)&hws, (void*)&out};
        hipError_t err = hipLaunchCooperativeKernel((const void*)ema_fused,
                                                    dim3(NCHUNK * 8), dim3(256),
                                                    args, 0, stream);
        if (err != hipSuccess) {
            // cooperative launch rejected (e.g. capture limitation) -> 3-kernel path
            ema_agg <<<dim3(NCHUNK * 8), dim3(256), 0, stream>>>(x, ld, hws);
            ema_scan<<<dim3(SLICE / 256), dim3(256), 0, stream>>>(x, ld, hws);
            ema_main<<<dim3(NCHUNK * 8), dim3(256), 0, stream>>>(x, ld, hws, out);
        }
    } else {
        ema_kernel<<<dim3(NCHUNK * 8), dim3(256), 0, stream>>>(x, ld, out);
    }
}

// Round 3
// 434.289 us; speedup vs baseline: 1.5305x; 1.5305x over previous
//
#include <hip/hip_runtime.h>

// EMA scan: out[l,b,d,e] = dec[e]*x[l,b,d] + (1-dec[e])*out[l-1,b,d,e],
// init state = x[0,b,d]. dec = sigmoid(log_decay).
//
// R9: single kernel, exact chunk-carry decomposition, HOMEMADE grid barrier.
//   R8's cooperative grid.sync() forced VGPR=64 -> xv[32] spilled to scratch
//   (FETCH 174MB, 655us). Fix: device-scope atomic counter barrier in ws,
//   nothing big kept live across barriers (phase 3 re-reads x from L3).
//   __launch_bounds__(256,4) caps VGPR at 128 -> 4 blocks/CU -> all 1024
//   blocks co-resident -> spin barrier is deadlock-free by construction.
//   Barrier counters at ws+8MiB, zeroed per launch via hipMemsetAsync
//   (graph-capture legal). Fallbacks: R7 3-kernel path, then R6 halo kernel.

#define LL    4096
#define BB    16
#define DD    128
#define EMAS  8
#define BDSZ  (BB * DD)              // 2048
#define CHUNK 32
#define NCHUNK (LL / CHUNK)          // 128
#define SLICE (BDSZ * EMAS)          // 16384 floats per chunk slice in ws
#define WS_BYTES ((size_t)NCHUNK * SLICE * sizeof(float))   // 8 MiB carries
#define WS_TOTAL (WS_BYTES + 256)                           // + flag block

typedef float f32x4 __attribute__((ext_vector_type(4)));

__device__ __forceinline__ void load_decays(const float* __restrict__ log_decay,
                                            float* dec, float* a) {
#pragma unroll
    for (int e = 0; e < EMAS; ++e) {
        const float ld = log_decay[e];
        const float dd = 1.0f / (1.0f + __expf(-ld));
        dec[e] = dd;
        a[e]   = 1.0f - dd;
    }
}

__device__ __forceinline__ void bar_arrive(unsigned* ctr) {
    __threadfence();                 // make this thread's stores visible (device scope)
    __syncthreads();                 // all block stores fenced before the add
    if (threadIdx.x == 0)
        __hip_atomic_fetch_add(ctr, 1u, __ATOMIC_RELEASE, __HIP_MEMORY_SCOPE_AGENT);
}

__device__ __forceinline__ void bar_wait(unsigned* ctr, unsigned target) {
    if (threadIdx.x == 0) {
        while (__hip_atomic_load(ctr, __ATOMIC_ACQUIRE, __HIP_MEMORY_SCOPE_AGENT) < target)
            __builtin_amdgcn_s_sleep(2);
    }
    __syncthreads();
    __threadfence();                 // acquire: order subsequent loads
}

// ---------------- R9 fused kernel ----------------
__global__ __launch_bounds__(256, 4) void ema_one(const float* __restrict__ x,
                                                  const float* __restrict__ log_decay,
                                                  float* __restrict__ hws,
                                                  unsigned* __restrict__ flags,
                                                  float* __restrict__ out) {
    const int tid   = threadIdx.x;
    const int chunk = blockIdx.x >> 3;
    const int off   = ((blockIdx.x & 7) << 8) + tid;   // == b*DD + d

    unsigned* ctr1 = flags + 0;
    unsigned* ctr2 = flags + 16;     // separate cachelines

    // ---- Phase 1: per-chunk aggregate h_c (zero-init 32-step EMA) ----
    {
        float dec[EMAS], a[EMAS];
        load_decays(log_decay, dec, a);

        const float* xp = x + (size_t)chunk * CHUNK * BDSZ + off;
        float s[EMAS];
#pragma unroll
        for (int e = 0; e < EMAS; ++e) s[e] = 0.0f;
#pragma unroll
        for (int k = 0; k < CHUNK; ++k) {
            const float xk = xp[(size_t)k * BDSZ];
#pragma unroll
            for (int e = 0; e < EMAS; ++e) s[e] = fmaf(a[e], s[e], dec[e] * xk);
        }
        f32x4* hp = (f32x4*)(hws + (size_t)chunk * SLICE + (size_t)off * EMAS);
        f32x4 lo = {s[0], s[1], s[2], s[3]};
        f32x4 hi = {s[4], s[5], s[6], s[7]};
        hp[0] = lo;
        hp[1] = hi;
    }

    bar_arrive(ctr1);

    // ---- Phase 2: carry scan, blocks 0..63 only (16K threads = (b,d,e)) ----
    if (blockIdx.x < 64) {
        bar_wait(ctr1, (unsigned)gridDim.x);

        const int t  = blockIdx.x * 256 + tid;
        const int e  = t & (EMAS - 1);
        const int bd = t >> 3;

        const float ld2 = log_decay[e];
        const float d2  = 1.0f / (1.0f + __expf(-ld2));
        float A = 1.0f - d2;
        A = A * A; A = A * A; A = A * A; A = A * A; A = A * A;   // a^32

        float sc  = x[bd];           // carry into chunk 0 = x[0,b,d]
        float* hp = hws + t;

#define PF 16
        float buf[PF];
#pragma unroll
        for (int i = 0; i < PF; ++i) buf[i] = hp[(size_t)i * SLICE];
        for (int c0 = 0; c0 < NCHUNK; c0 += PF) {
            float nbuf[PF];
            if (c0 + PF < NCHUNK) {
#pragma unroll
                for (int i = 0; i < PF; ++i) nbuf[i] = hp[(size_t)(c0 + PF + i) * SLICE];
            } else {
#pragma unroll
                for (int i = 0; i < PF; ++i) nbuf[i] = 0.0f;
            }
#pragma unroll
            for (int i = 0; i < PF; ++i) {
                const float hv = buf[i];
                hp[(size_t)(c0 + i) * SLICE] = sc;   // publish carry into c0+i
                sc = fmaf(A, sc, hv);                // carry into next chunk
            }
#pragma unroll
            for (int i = 0; i < PF; ++i) buf[i] = nbuf[i];
        }
#undef PF
        bar_arrive(ctr2);
    }

    bar_wait(ctr2, 64u);

    // ---- Phase 3: read carry (32B) + x (L3-warm), pure store stream ----
    {
        float dec[EMAS], a[EMAS];
        load_decays(log_decay, dec, a);

        const f32x4* cp = (const f32x4*)(hws + (size_t)chunk * SLICE + (size_t)off * EMAS);
        f32x4 clo = cp[0];
        f32x4 chi = cp[1];
        float s[EMAS];
#pragma unroll
        for (int i = 0; i < 4; ++i) { s[i] = clo[i]; s[4 + i] = chi[i]; }

        const float* xp = x + (size_t)chunk * CHUNK * BDSZ + off;
        float xv[CHUNK];
#pragma unroll
        for (int k = 0; k < CHUNK; ++k) xv[k] = xp[(size_t)k * BDSZ];

        f32x4* op = (f32x4*)(out + ((size_t)chunk * CHUNK * BDSZ + off) * EMAS);
        const int opstride = SLICE / 4;          // f32x4s per l-step
#pragma unroll
        for (int k = 0; k < CHUNK; ++k) {
            const float xk = xv[k];
#pragma unroll
            for (int e = 0; e < EMAS; ++e) s[e] = fmaf(a[e], s[e], dec[e] * xk);
            f32x4 lo = {s[0], s[1], s[2], s[3]};
            f32x4 hi = {s[4], s[5], s[6], s[7]};
            op[0] = lo;
            op[1] = hi;
            op += opstride;
        }
    }
}

// ---------------- R7 fallback: 3-kernel exact path ----------------
__global__ __launch_bounds__(256) void ema_agg(const float* __restrict__ x,
                                               const float* __restrict__ log_decay,
                                               float* __restrict__ hws) {
    const int tid   = threadIdx.x;
    const int chunk = blockIdx.x >> 3;
    const int off   = ((blockIdx.x & 7) << 8) + tid;

    float dec[EMAS], a[EMAS];
    load_decays(log_decay, dec, a);

    const float* xp = x + (size_t)chunk * CHUNK * BDSZ + off;
    float s[EMAS];
#pragma unroll
    for (int e = 0; e < EMAS; ++e) s[e] = 0.0f;
#pragma unroll
    for (int k = 0; k < CHUNK; ++k) {
        const float xk = xp[(size_t)k * BDSZ];
#pragma unroll
        for (int e = 0; e < EMAS; ++e) s[e] = fmaf(a[e], s[e], dec[e] * xk);
    }

    f32x4* hp = (f32x4*)(hws + (size_t)chunk * SLICE + (size_t)off * EMAS);
    f32x4 lo = {s[0], s[1], s[2], s[3]};
    f32x4 hi = {s[4], s[5], s[6], s[7]};
    hp[0] = lo;
    hp[1] = hi;
}

__global__ __launch_bounds__(256) void ema_scan(const float* __restrict__ x,
                                                const float* __restrict__ log_decay,
                                                float* __restrict__ hws) {
    const int tid = blockIdx.x * 256 + threadIdx.x;
    const int e   = tid & (EMAS - 1);
    const int bd  = tid >> 3;

    const float ld  = log_decay[e];
    const float dec = 1.0f / (1.0f + __expf(-ld));
    float A = 1.0f - dec;
    A = A * A; A = A * A; A = A * A; A = A * A; A = A * A;   // a^32

    float s = x[bd];
    float* hp = hws + tid;

#define PF 16
    float buf[PF];
#pragma unroll
    for (int i = 0; i < PF; ++i) buf[i] = hp[(size_t)i * SLICE];
    for (int c0 = 0; c0 < NCHUNK; c0 += PF) {
        float nbuf[PF];
        if (c0 + PF < NCHUNK) {
#pragma unroll
            for (int i = 0; i < PF; ++i) nbuf[i] = hp[(size_t)(c0 + PF + i) * SLICE];
        } else {
#pragma unroll
            for (int i = 0; i < PF; ++i) nbuf[i] = 0.0f;
        }
#pragma unroll
        for (int i = 0; i < PF; ++i) {
            const float hv = buf[i];
            hp[(size_t)(c0 + i) * SLICE] = s;
            s = fmaf(A, s, hv);
        }
#pragma unroll
        for (int i = 0; i < PF; ++i) buf[i] = nbuf[i];
    }
#undef PF
}

__global__ __launch_bounds__(256) void ema_main(const float* __restrict__ x,
                                                const float* __restrict__ log_decay,
                                                const float* __restrict__ carry,
                                                float* __restrict__ out) {
    const int tid   = threadIdx.x;
    const int chunk = blockIdx.x >> 3;
    const int off   = ((blockIdx.x & 7) << 8) + tid;

    float dec[EMAS], a[EMAS];
    load_decays(log_decay, dec, a);

    const f32x4* cp = (const f32x4*)(carry + (size_t)chunk * SLICE + (size_t)off * EMAS);
    f32x4 clo = cp[0];
    f32x4 chi = cp[1];
    float s[EMAS];
#pragma unroll
    for (int i = 0; i < 4; ++i) { s[i] = clo[i]; s[4 + i] = chi[i]; }

    const float* xp = x + (size_t)chunk * CHUNK * BDSZ + off;
    float xv[CHUNK];
#pragma unroll
    for (int k = 0; k < CHUNK; ++k) xv[k] = xp[(size_t)k * BDSZ];

    f32x4* op = (f32x4*)(out + ((size_t)chunk * CHUNK * BDSZ + off) * EMAS);
    const int opstride = SLICE / 4;
#pragma unroll
    for (int k = 0; k < CHUNK; ++k) {
        const float xk = xv[k];
#pragma unroll
        for (int e = 0; e < EMAS; ++e) s[e] = fmaf(a[e], s[e], dec[e] * xk);
        f32x4 lo = {s[0], s[1], s[2], s[3]};
        f32x4 hi = {s[4], s[5], s[6], s[7]};
        op[0] = lo;
        op[1] = hi;
        op += opstride;
    }
}

// ---------------- Last-resort fallback: R6 halo kernel (no ws) ----------------
#define HALO  128
#define U     16

__global__ __launch_bounds__(256) void ema_kernel(const float* __restrict__ x,
                                                  const float* __restrict__ log_decay,
                                                  float* __restrict__ out) {
    const int tid   = threadIdx.x;
    const int d     = tid & (DD - 1);
    const int bsub  = tid >> 7;
    const int bg    = blockIdx.x & 7;
    const int chunk = blockIdx.x >> 3;
    const int b     = bg * 2 + bsub;
    const int off   = b * DD + d;

    float dec[EMAS], a[EMAS];
    load_decays(log_decay, dec, a);

    const int cstart = chunk * CHUNK;
    int l0 = cstart - HALO;
    if (l0 < 0) l0 = 0;
    const int nsteps   = (cstart - l0) + CHUNK;
    const int nblk     = nsteps / U;
    const int halo_blk = (cstart - l0) / U;

    const float* xb = x + (size_t)l0 * BDSZ + off;

    const float s0 = *xb;
    float s[EMAS];
#pragma unroll
    for (int e = 0; e < EMAS; ++e) s[e] = s0;

    f32x4* op = (f32x4*)(out + ((size_t)cstart * BDSZ + off) * EMAS);
    const int opstride = BDSZ * EMAS / 4;

#define LOADBLK(BUF, IDX)                                                      \
    do {                                                                       \
        int _i = (IDX); if (_i > nblk - 1) _i = nblk - 1;                      \
        const float* _p = xb + (size_t)_i * U * BDSZ;                          \
        _Pragma("unroll")                                                      \
        for (int u = 0; u < U; ++u) (BUF)[u] = _p[(size_t)u * BDSZ];           \
    } while (0)

#define PROCESS(BUF, J)                                                        \
    do {                                                                       \
        if ((J) >= halo_blk) {                                                 \
            _Pragma("unroll")                                                  \
            for (int u = 0; u < U; ++u) {                                      \
                const float xv2 = (BUF)[u];                                    \
                _Pragma("unroll")                                              \
                for (int e = 0; e < EMAS; ++e)                                 \
                    s[e] = fmaf(a[e], s[e], dec[e] * xv2);                     \
                f32x4 lo = {s[0], s[1], s[2], s[3]};                           \
                f32x4 hi = {s[4], s[5], s[6], s[7]};                           \
                op[0] = lo;                                                    \
                op[1] = hi;                                                    \
                op += opstride;                                                \
            }                                                                  \
        } else {                                                               \
            _Pragma("unroll")                                                  \
            for (int u = 0; u < U; ++u) {                                      \
                const float xv2 = (BUF)[u];                                    \
                _Pragma("unroll")                                              \
                for (int e = 0; e < EMAS; ++e)                                 \
                    s[e] = fmaf(a[e], s[e], dec[e] * xv2);                     \
            }                                                                  \
        }                                                                      \
    } while (0)

    float b0[U], b1[U], b2[U];
    LOADBLK(b0, 0);
    LOADBLK(b1, 1);

    int j = 0;
    for (; j + 2 < nblk; j += 3) {
        LOADBLK(b2, j + 2);
        PROCESS(b0, j);
        LOADBLK(b0, j + 3);
        PROCESS(b1, j + 1);
        LOADBLK(b1, j + 4);
        PROCESS(b2, j + 2);
    }
    if (j < nblk)     PROCESS(b0, j);
    if (j + 1 < nblk) PROCESS(b1, j + 1);
#undef PROCESS
#undef LOADBLK
}

extern "C" void kernel_launch(void* const* d_in, const int* in_sizes, int n_in,
                              void* d_out, int out_size, void* d_ws, size_t ws_size,
                              hipStream_t stream) {
    const float* x  = (const float*)d_in[0];
    const float* ld = (const float*)d_in[1];
    float* out      = (float*)d_out;
    (void)in_sizes; (void)n_in; (void)out_size;

    if (d_ws && ws_size >= WS_TOTAL) {
        float* hws      = (float*)d_ws;
        unsigned* flags = (unsigned*)((char*)d_ws + WS_BYTES);
        hipMemsetAsync((void*)flags, 0, 256, stream);   // reset barrier counters
        ema_one<<<dim3(NCHUNK * 8), dim3(256), 0, stream>>>(x, ld, hws, flags, out);
    } else if (d_ws && ws_size >= WS_BYTES) {
        float* hws = (float*)d_ws;
        ema_agg <<<dim3(NCHUNK * 8), dim3(256), 0, stream>>>(x, ld, hws);
        ema_scan<<<dim3(SLICE / 256), dim3(256), 0, stream>>>(x, ld, hws);
        ema_main<<<dim3(NCHUNK * 8), dim3(256), 0, stream>>>(x, ld, hws, out);
    } else {
        ema_kernel<<<dim3(NCHUNK * 8), dim3(256), 0, stream>>>(x, ld, out);
    }
}